// Round 18
// baseline (111.513 us; speedup 1.0000x reference)
//
#include <hip/hip_runtime.h>

#define HD 256
#define LN_EPS 1e-5f
#define DEG_EPS 1e-6f
#define CAP 64

typedef __attribute__((ext_vector_type(8))) short short8;
typedef __attribute__((ext_vector_type(4))) short s16x4;
typedef __attribute__((ext_vector_type(4))) float f32x4;
typedef __attribute__((ext_vector_type(4))) int i32x4;

__device__ inline unsigned short f2bf(float f) {
    union { float f; unsigned int u; } v; v.f = f;
    unsigned int r = v.u + 0x7FFFu + ((v.u >> 16) & 1u);
    return (unsigned short)(r >> 16);
}
__device__ inline float bf2f(unsigned short h) {
    union { unsigned int u; float f; } v; v.u = ((unsigned int)h) << 16;
    return v.f;
}
__device__ inline short8 cvt8(float4 u0, float4 u1) {
    short8 o;
    o[0] = (short)f2bf(u0.x); o[1] = (short)f2bf(u0.y);
    o[2] = (short)f2bf(u0.z); o[3] = (short)f2bf(u0.w);
    o[4] = (short)f2bf(u1.x); o[5] = (short)f2bf(u1.y);
    o[6] = (short)f2bf(u1.z); o[7] = (short)f2bf(u1.w);
    return o;
}

// Blocks [0,zb): zero counts. Blocks [zb, zb+256): W12 = W2[:, :256]@W1
// (fp32 accumulate -> bf16), bv = W2@b1, ucol = clue column of W2.
__global__ __launch_bounds__(256) void prep0_kernel(
    int* __restrict__ counts, int num_con,
    const float* __restrict__ msg_W, const float* __restrict__ msg_b,
    const float* __restrict__ upd_W,
    unsigned short* __restrict__ w12b, float* __restrict__ bv,
    float* __restrict__ ucol, int zb) {
    int b = blockIdx.x, tid = threadIdx.x;
    if (b < zb) {
        int i = (b * 256 + tid) * 4;
        if (i + 4 <= num_con) *(i32x4*)(counts + i) = (i32x4){0, 0, 0, 0};
        else for (; i < num_con; ++i) counts[i] = 0;
    } else {
        int j = b - zb, k = tid;
        float a0 = 0.f, a1 = 0.f, a2 = 0.f, a3 = 0.f, accb = 0.f;
#pragma unroll 2
        for (int m = 0; m < 256; m += 4) {
            float w0 = upd_W[j * 257 + m + 0];
            float w1 = upd_W[j * 257 + m + 1];
            float w2 = upd_W[j * 257 + m + 2];
            float w3 = upd_W[j * 257 + m + 3];
            a0 = fmaf(w0, msg_W[(m + 0) * 256 + k], a0);
            a1 = fmaf(w1, msg_W[(m + 1) * 256 + k], a1);
            a2 = fmaf(w2, msg_W[(m + 2) * 256 + k], a2);
            a3 = fmaf(w3, msg_W[(m + 3) * 256 + k], a3);
            accb = fmaf(w0, msg_b[m + 0], accb);
            accb = fmaf(w1, msg_b[m + 1], accb);
            accb = fmaf(w2, msg_b[m + 2], accb);
            accb = fmaf(w3, msg_b[m + 3], accb);
        }
        w12b[j * 256 + k] = f2bf((a0 + a1) + (a2 + a3));
        if (k == 0) { bv[j] = accb; ucol[j] = upd_W[j * 257 + 256]; }
    }
}

// Bucket edges by dst: counts[] = degree, eidx[d*CAP + p] = src ids.
__global__ __launch_bounds__(256) void fill_kernel(
    const int* __restrict__ src, const int* __restrict__ dst,
    int* __restrict__ counts, int* __restrict__ eidx, int E) {
    int e = blockIdx.x * 256 + threadIdx.x;
    if (e >= E) return;
    int d = dst[e];
    int p = atomicAdd(&counts[d], 1);
    if (p < CAP) eidx[d * CAP + p] = src[e];
}

// y = bf16(x @ W12^T) in PERMUTED layout (col' = w*64+lr*4+jt holds true
// col w*64+jt*16+lr). T14 async-stage: tile t+1's fp32 A is loaded into
// registers BEFORE the barrier (lands under tile t's MFMA+store), written
// to LDS at the next loop top. One barrier per tile, double-buffered sA.
__global__ __launch_bounds__(256) void ygemm_kernel(
    const float* __restrict__ x, const unsigned short* __restrict__ w12b,
    unsigned short* __restrict__ y, int n_var, int ntiles) {

    __shared__ unsigned short sA[2][16 * 256];   // 2 x 8 KB swizzled bf16 A
    const int tid = threadIdx.x, w = tid >> 6, lane = tid & 63;
    const int lr = lane & 15, lg = lane >> 4;

    short8 bfr[4][8];
#pragma unroll
    for (int jt = 0; jt < 4; ++jt)
#pragma unroll
        for (int ks = 0; ks < 8; ++ks)
            bfr[jt][ks] = *(const short8*)(w12b + (w * 64 + jt * 16 + lr) * HD + lg * 8 + ks * 32);

    const int srow = tid >> 4, scol = (tid & 15) * 16;   // stage: 16 thr/row
    const int b0 = (srow * 512 + scol * 2) ^ ((srow & 7) << 4);
    const int b1 = (srow * 512 + scol * 2 + 16) ^ ((srow & 7) << 4);

    int rt = blockIdx.x;
    float4 u0, u1, u2, u3;
    if (rt < ntiles) {
        int arc = min(rt * 16 + srow, n_var - 1);
        const float* gp = x + (long)arc * HD + scol;
        u0 = *(const float4*)(gp);
        u1 = *(const float4*)(gp + 4);
        u2 = *(const float4*)(gp + 8);
        u3 = *(const float4*)(gp + 12);
    }

    int buf = 0;
#pragma unroll 1
    for (; rt < ntiles; ) {
        int r0 = rt * 16;
        // ---- write the prefetched (already in-register) tile to LDS ----
        *(short8*)((char*)&sA[buf][0] + b0) = cvt8(u0, u1);
        *(short8*)((char*)&sA[buf][0] + b1) = cvt8(u2, u3);

        // ---- issue next tile's global loads (land under compute) ----
        int nrt = rt + gridDim.x;
        {
            int prt = min(nrt, ntiles - 1);
            int arc = min(prt * 16 + srow, n_var - 1);
            const float* gp = x + (long)arc * HD + scol;
            u0 = *(const float4*)(gp);
            u1 = *(const float4*)(gp + 4);
            u2 = *(const float4*)(gp + 8);
            u3 = *(const float4*)(gp + 12);
        }
        __syncthreads();

        short8 af[8];
#pragma unroll
        for (int ks = 0; ks < 8; ++ks) {
            int byte = (lr * 512 + (ks * 32 + lg * 8) * 2) ^ ((lr & 7) << 4);
            af[ks] = *(const short8*)((char*)&sA[buf][0] + byte);
        }

        f32x4 acc[4] = {{0.f,0.f,0.f,0.f},{0.f,0.f,0.f,0.f},{0.f,0.f,0.f,0.f},{0.f,0.f,0.f,0.f}};
#pragma unroll
        for (int ks = 0; ks < 8; ++ks)
#pragma unroll
            for (int jt = 0; jt < 4; ++jt)
                acc[jt] = __builtin_amdgcn_mfma_f32_16x16x32_bf16(af[ks], bfr[jt][ks], acc[jt], 0, 0, 0);

        // ---- direct permuted store: lane packs its 4 jt-values per row ----
#pragma unroll
        for (int q = 0; q < 4; ++q) {
            int grow = r0 + lg * 4 + q;
            if (grow < n_var) {
                s16x4 o;
#pragma unroll
                for (int jt = 0; jt < 4; ++jt) o[jt] = (short)f2bf(acc[jt][q]);
                *(s16x4*)(y + (long)grow * HD + w * 64 + lr * 4) = o;
            }
        }
        buf ^= 1;
        rt = nrt;
    }
}

// Gather + epilogue. y is in permuted layout: component jt of the 8B read
// at col' = lane*4 corresponds to TRUE col c_jt = (lane>>4)*64 + jt*16 +
// (lane&15). Per-col params are loaded at c_jt; LN sum is col-order
// agnostic; out stores go to the true cols.
__global__ __launch_bounds__(256) void gatherln_kernel(
    const unsigned short* __restrict__ y, const int* __restrict__ counts,
    const int* __restrict__ eidx, const float* __restrict__ clue,
    const float* __restrict__ bv, const float* __restrict__ ucol,
    const float* __restrict__ upd_b,
    const float* __restrict__ ln_w, const float* __restrict__ ln_b,
    float* __restrict__ out, int num_con) {
    int row  = blockIdx.x * 4 + (threadIdx.x >> 6);
    int lane = threadIdx.x & 63;
    if (row >= num_con) return;
    int cnt = counts[row];
    int cgo = min(cnt, CAP);
    int sid = (lane < cgo) ? eidx[row * CAP + lane] : 0;
    float a0 = 0.f, a1 = 0.f, a2 = 0.f, a3 = 0.f;
#pragma unroll 1
    for (int i = 0; i < cgo; i += 8) {
        int s[8];
#pragma unroll
        for (int u = 0; u < 8; ++u) s[u] = __shfl(sid, i + u, 64);
        s16x4 v[8];
#pragma unroll
        for (int u = 0; u < 8; ++u)
            v[u] = *(const s16x4*)(y + (long)s[u] * HD + lane * 4);
#pragma unroll
        for (int u = 0; u < 8; ++u) {
            float wg = (i + u < cgo) ? 1.f : 0.f;
            a0 = fmaf(bf2f((unsigned short)v[u][0]), wg, a0);
            a1 = fmaf(bf2f((unsigned short)v[u][1]), wg, a1);
            a2 = fmaf(bf2f((unsigned short)v[u][2]), wg, a2);
            a3 = fmaf(bf2f((unsigned short)v[u][3]), wg, a3);
        }
    }
    // true cols for components 0..3
    int c0 = ((lane >> 4) << 6) + (lane & 15);   // + jt*16
    float sc = 1.0f / ((float)cnt + DEG_EPS);
    float tc = (float)cnt * sc;
    float cl = clue[row];
    float z[4] = {a0, a1, a2, a3};
    float s = 0.f, s2 = 0.f;
#pragma unroll
    for (int jt = 0; jt < 4; ++jt) {
        int c = c0 + jt * 16;
        float zz = fmaxf(z[jt] * sc + tc * bv[c] + cl * ucol[c] + upd_b[c], 0.0f);
        z[jt] = zz;
        s += zz; s2 += zz * zz;
    }
#pragma unroll
    for (int m = 1; m < 64; m <<= 1) {
        s  += __shfl_xor(s,  m, 64);
        s2 += __shfl_xor(s2, m, 64);
    }
    float mu = s * (1.0f / HD);
    float var = s2 * (1.0f / HD) - mu * mu;
    float rs = rsqrtf(var + LN_EPS);
    float* gp = out + (long)row * HD;
#pragma unroll
    for (int jt = 0; jt < 4; ++jt) {
        int c = c0 + jt * 16;
        gp[c] = (z[jt] - mu) * rs * ln_w[c] + ln_b[c];
    }
}

extern "C" void kernel_launch(void* const* d_in, const int* in_sizes, int n_in,
                              void* d_out, int out_size, void* d_ws, size_t ws_size,
                              hipStream_t stream) {
    const float* x_var = (const float*)d_in[0];
    const int*   src   = (const int*)d_in[1];
    const int*   dst   = (const int*)d_in[2];
    const float* clue  = (const float*)d_in[3];
    // d_in[4] = num_con scalar (derived from out_size instead)
    const float* msg_W = (const float*)d_in[5];
    const float* msg_b = (const float*)d_in[6];
    const float* upd_W = (const float*)d_in[7];
    const float* upd_b = (const float*)d_in[8];
    const float* ln_w  = (const float*)d_in[9];
    const float* ln_b  = (const float*)d_in[10];

    int E = in_sizes[1];
    long n_x = in_sizes[0];
    int n_var = (int)(n_x / HD);
    int num_con = out_size / HD;
    int ntiles_v = (n_var + 15) / 16;

    char* ws = (char*)d_ws;
    int* counts = (int*)ws;                               // num_con ints
    int* eidx   = (int*)(ws + (((size_t)num_con * 4 + 255) & ~(size_t)255));
    char* after = (char*)(eidx + (size_t)num_con * CAP);  // num_con*CAP ints
    size_t yoff = ((size_t)(after - ws) + 255) & ~(size_t)255;
    unsigned short* yv = (unsigned short*)(ws + yoff);    // n_var*256 bf16 (permuted)
    size_t woff = (yoff + (size_t)n_var * HD * 2 + 255) & ~(size_t)255;
    unsigned short* w12b = (unsigned short*)(ws + woff);  // 256*256 bf16
    float* bvp  = (float*)(w12b + 256 * 256);             // 256 fp32
    float* ucol = bvp + 256;                              // 256 fp32

    int zb = (num_con + 1023) / 1024;
    prep0_kernel<<<zb + 256, 256, 0, stream>>>(
        counts, num_con, msg_W, msg_b, upd_W, w12b, bvp, ucol, zb);

    fill_kernel<<<(E + 255) / 256, 256, 0, stream>>>(src, dst, counts, eidx, E);

    ygemm_kernel<<<2048, 256, 0, stream>>>(x_var, w12b, yv, n_var, ntiles_v);

    gatherln_kernel<<<(num_con + 3) / 4, 256, 0, stream>>>(
        yv, counts, eidx, clue, bvp, ucol, upd_b, ln_w, ln_b,
        (float*)d_out, num_con);
}

// Round 19
// 103.573 us; speedup vs baseline: 1.0767x; 1.0767x over previous
//
#include <hip/hip_runtime.h>

#define HD 256
#define LN_EPS 1e-5f
#define DEG_EPS 1e-6f
#define CAP 64

typedef __attribute__((ext_vector_type(8))) short short8;
typedef __attribute__((ext_vector_type(4))) short s16x4;
typedef __attribute__((ext_vector_type(4))) float f32x4;
typedef __attribute__((ext_vector_type(4))) int i32x4;

__device__ inline unsigned short f2bf(float f) {
    union { float f; unsigned int u; } v; v.f = f;
    unsigned int r = v.u + 0x7FFFu + ((v.u >> 16) & 1u);
    return (unsigned short)(r >> 16);
}
__device__ inline float bf2f(unsigned short h) {
    union { unsigned int u; float f; } v; v.u = ((unsigned int)h) << 16;
    return v.f;
}
__device__ inline short8 cvt8(float4 u0, float4 u1) {
    short8 o;
    o[0] = (short)f2bf(u0.x); o[1] = (short)f2bf(u0.y);
    o[2] = (short)f2bf(u0.z); o[3] = (short)f2bf(u0.w);
    o[4] = (short)f2bf(u1.x); o[5] = (short)f2bf(u1.y);
    o[6] = (short)f2bf(u1.z); o[7] = (short)f2bf(u1.w);
    return o;
}

// Blocks [0,zb): zero counts. Blocks [zb, zb+256): W12 = W2[:, :256]@W1
// (fp32 accumulate -> bf16), bv = W2@b1, ucol = clue column of W2.
__global__ __launch_bounds__(256) void prep0_kernel(
    int* __restrict__ counts, int num_con,
    const float* __restrict__ msg_W, const float* __restrict__ msg_b,
    const float* __restrict__ upd_W,
    unsigned short* __restrict__ w12b, float* __restrict__ bv,
    float* __restrict__ ucol, int zb) {
    int b = blockIdx.x, tid = threadIdx.x;
    if (b < zb) {
        int i = (b * 256 + tid) * 4;
        if (i + 4 <= num_con) *(i32x4*)(counts + i) = (i32x4){0, 0, 0, 0};
        else for (; i < num_con; ++i) counts[i] = 0;
    } else {
        int j = b - zb, k = tid;
        float a0 = 0.f, a1 = 0.f, a2 = 0.f, a3 = 0.f, accb = 0.f;
#pragma unroll 2
        for (int m = 0; m < 256; m += 4) {
            float w0 = upd_W[j * 257 + m + 0];
            float w1 = upd_W[j * 257 + m + 1];
            float w2 = upd_W[j * 257 + m + 2];
            float w3 = upd_W[j * 257 + m + 3];
            a0 = fmaf(w0, msg_W[(m + 0) * 256 + k], a0);
            a1 = fmaf(w1, msg_W[(m + 1) * 256 + k], a1);
            a2 = fmaf(w2, msg_W[(m + 2) * 256 + k], a2);
            a3 = fmaf(w3, msg_W[(m + 3) * 256 + k], a3);
            accb = fmaf(w0, msg_b[m + 0], accb);
            accb = fmaf(w1, msg_b[m + 1], accb);
            accb = fmaf(w2, msg_b[m + 2], accb);
            accb = fmaf(w3, msg_b[m + 3], accb);
        }
        w12b[j * 256 + k] = f2bf((a0 + a1) + (a2 + a3));
        if (k == 0) { bv[j] = accb; ucol[j] = upd_W[j * 257 + 256]; }
    }
}

// Bucket edges by dst: counts[] = degree, eidx[d*CAP + p] = src ids.
__global__ __launch_bounds__(256) void fill_kernel(
    const int* __restrict__ src, const int* __restrict__ dst,
    int* __restrict__ counts, int* __restrict__ eidx, int E) {
    int e = blockIdx.x * 256 + threadIdx.x;
    if (e >= E) return;
    int d = dst[e];
    int p = atomicAdd(&counts[d], 1);
    if (p < CAP) eidx[d * CAP + p] = src[e];
}

// y = bf16(x @ W12^T) in PERMUTED layout (col' = w*64+lr*4+jt holds true
// col w*64+jt*16+lr). Corrected T14 schedule: per tile,
//   LDS-write(t) -> barrier (nothing in flight) -> issue loads(t+1)
//   -> ds_read+MFMA+store(t)
// so loads(t+1) stay in flight across the whole compute phase instead of
// being drained by the compiler's vmcnt(0)-before-s_barrier.
__global__ __launch_bounds__(256) void ygemm_kernel(
    const float* __restrict__ x, const unsigned short* __restrict__ w12b,
    unsigned short* __restrict__ y, int n_var, int ntiles) {

    __shared__ unsigned short sA[2][16 * 256];   // 2 x 8 KB swizzled bf16 A
    const int tid = threadIdx.x, w = tid >> 6, lane = tid & 63;
    const int lr = lane & 15, lg = lane >> 4;

    short8 bfr[4][8];
#pragma unroll
    for (int jt = 0; jt < 4; ++jt)
#pragma unroll
        for (int ks = 0; ks < 8; ++ks)
            bfr[jt][ks] = *(const short8*)(w12b + (w * 64 + jt * 16 + lr) * HD + lg * 8 + ks * 32);

    const int srow = tid >> 4, scol = (tid & 15) * 16;   // stage: 16 thr/row
    const int b0 = (srow * 512 + scol * 2) ^ ((srow & 7) << 4);
    const int b1 = (srow * 512 + scol * 2 + 16) ^ ((srow & 7) << 4);

    int rt = blockIdx.x;
    float4 u0, u1, u2, u3;
    if (rt < ntiles) {
        int arc = min(rt * 16 + srow, n_var - 1);
        const float* gp = x + (long)arc * HD + scol;
        u0 = *(const float4*)(gp);
        u1 = *(const float4*)(gp + 4);
        u2 = *(const float4*)(gp + 8);
        u3 = *(const float4*)(gp + 12);
    }

    int buf = 0;
#pragma unroll 1
    for (; rt < ntiles; ) {
        int r0 = rt * 16;
        // ---- write the prefetched (in-register) tile to LDS ----
        *(short8*)((char*)&sA[buf][0] + b0) = cvt8(u0, u1);
        *(short8*)((char*)&sA[buf][0] + b1) = cvt8(u2, u3);

        // ---- barrier BEFORE issuing next loads: the compiler's vmcnt(0)
        // drain here has nothing outstanding (prev loads consumed above,
        // prev stores long retired) ----
        __syncthreads();

        // ---- issue next tile's global loads: now they stay in flight
        // across ds_read+MFMA+store below ----
        int nrt = rt + gridDim.x;
        {
            int prt = min(nrt, ntiles - 1);
            int arc = min(prt * 16 + srow, n_var - 1);
            const float* gp = x + (long)arc * HD + scol;
            u0 = *(const float4*)(gp);
            u1 = *(const float4*)(gp + 4);
            u2 = *(const float4*)(gp + 8);
            u3 = *(const float4*)(gp + 12);
        }

        short8 af[8];
#pragma unroll
        for (int ks = 0; ks < 8; ++ks) {
            int byte = (lr * 512 + (ks * 32 + lg * 8) * 2) ^ ((lr & 7) << 4);
            af[ks] = *(const short8*)((char*)&sA[buf][0] + byte);
        }

        f32x4 acc[4] = {{0.f,0.f,0.f,0.f},{0.f,0.f,0.f,0.f},{0.f,0.f,0.f,0.f},{0.f,0.f,0.f,0.f}};
#pragma unroll
        for (int ks = 0; ks < 8; ++ks)
#pragma unroll
            for (int jt = 0; jt < 4; ++jt)
                acc[jt] = __builtin_amdgcn_mfma_f32_16x16x32_bf16(af[ks], bfr[jt][ks], acc[jt], 0, 0, 0);

        // ---- direct permuted store: lane packs its 4 jt-values per row ----
#pragma unroll
        for (int q = 0; q < 4; ++q) {
            int grow = r0 + lg * 4 + q;
            if (grow < n_var) {
                s16x4 o;
#pragma unroll
                for (int jt = 0; jt < 4; ++jt) o[jt] = (short)f2bf(acc[jt][q]);
                *(s16x4*)(y + (long)grow * HD + w * 64 + lr * 4) = o;
            }
        }
        buf ^= 1;
        rt = nrt;
    }
}

// Gather + epilogue. y is in permuted layout: component jt of the 8B read
// at col' = lane*4 corresponds to TRUE col c_jt = (lane>>4)*64 + jt*16 +
// (lane&15). Per-col params are loaded at c_jt; LN sum is col-order
// agnostic; out stores go to the true cols.
__global__ __launch_bounds__(256) void gatherln_kernel(
    const unsigned short* __restrict__ y, const int* __restrict__ counts,
    const int* __restrict__ eidx, const float* __restrict__ clue,
    const float* __restrict__ bv, const float* __restrict__ ucol,
    const float* __restrict__ upd_b,
    const float* __restrict__ ln_w, const float* __restrict__ ln_b,
    float* __restrict__ out, int num_con) {
    int row  = blockIdx.x * 4 + (threadIdx.x >> 6);
    int lane = threadIdx.x & 63;
    if (row >= num_con) return;
    int cnt = counts[row];
    int cgo = min(cnt, CAP);
    int sid = (lane < cgo) ? eidx[row * CAP + lane] : 0;
    float a0 = 0.f, a1 = 0.f, a2 = 0.f, a3 = 0.f;
#pragma unroll 1
    for (int i = 0; i < cgo; i += 8) {
        int s[8];
#pragma unroll
        for (int u = 0; u < 8; ++u) s[u] = __shfl(sid, i + u, 64);
        s16x4 v[8];
#pragma unroll
        for (int u = 0; u < 8; ++u)
            v[u] = *(const s16x4*)(y + (long)s[u] * HD + lane * 4);
#pragma unroll
        for (int u = 0; u < 8; ++u) {
            float wg = (i + u < cgo) ? 1.f : 0.f;
            a0 = fmaf(bf2f((unsigned short)v[u][0]), wg, a0);
            a1 = fmaf(bf2f((unsigned short)v[u][1]), wg, a1);
            a2 = fmaf(bf2f((unsigned short)v[u][2]), wg, a2);
            a3 = fmaf(bf2f((unsigned short)v[u][3]), wg, a3);
        }
    }
    // true cols for components 0..3
    int c0 = ((lane >> 4) << 6) + (lane & 15);   // + jt*16
    float sc = 1.0f / ((float)cnt + DEG_EPS);
    float tc = (float)cnt * sc;
    float cl = clue[row];
    float z[4] = {a0, a1, a2, a3};
    float s = 0.f, s2 = 0.f;
#pragma unroll
    for (int jt = 0; jt < 4; ++jt) {
        int c = c0 + jt * 16;
        float zz = fmaxf(z[jt] * sc + tc * bv[c] + cl * ucol[c] + upd_b[c], 0.0f);
        z[jt] = zz;
        s += zz; s2 += zz * zz;
    }
#pragma unroll
    for (int m = 1; m < 64; m <<= 1) {
        s  += __shfl_xor(s,  m, 64);
        s2 += __shfl_xor(s2, m, 64);
    }
    float mu = s * (1.0f / HD);
    float var = s2 * (1.0f / HD) - mu * mu;
    float rs = rsqrtf(var + LN_EPS);
    float* gp = out + (long)row * HD;
#pragma unroll
    for (int jt = 0; jt < 4; ++jt) {
        int c = c0 + jt * 16;
        gp[c] = (z[jt] - mu) * rs * ln_w[c] + ln_b[c];
    }
}

extern "C" void kernel_launch(void* const* d_in, const int* in_sizes, int n_in,
                              void* d_out, int out_size, void* d_ws, size_t ws_size,
                              hipStream_t stream) {
    const float* x_var = (const float*)d_in[0];
    const int*   src   = (const int*)d_in[1];
    const int*   dst   = (const int*)d_in[2];
    const float* clue  = (const float*)d_in[3];
    // d_in[4] = num_con scalar (derived from out_size instead)
    const float* msg_W = (const float*)d_in[5];
    const float* msg_b = (const float*)d_in[6];
    const float* upd_W = (const float*)d_in[7];
    const float* upd_b = (const float*)d_in[8];
    const float* ln_w  = (const float*)d_in[9];
    const float* ln_b  = (const float*)d_in[10];

    int E = in_sizes[1];
    long n_x = in_sizes[0];
    int n_var = (int)(n_x / HD);
    int num_con = out_size / HD;
    int ntiles_v = (n_var + 15) / 16;

    char* ws = (char*)d_ws;
    int* counts = (int*)ws;                               // num_con ints
    int* eidx   = (int*)(ws + (((size_t)num_con * 4 + 255) & ~(size_t)255));
    char* after = (char*)(eidx + (size_t)num_con * CAP);  // num_con*CAP ints
    size_t yoff = ((size_t)(after - ws) + 255) & ~(size_t)255;
    unsigned short* yv = (unsigned short*)(ws + yoff);    // n_var*256 bf16 (permuted)
    size_t woff = (yoff + (size_t)n_var * HD * 2 + 255) & ~(size_t)255;
    unsigned short* w12b = (unsigned short*)(ws + woff);  // 256*256 bf16
    float* bvp  = (float*)(w12b + 256 * 256);             // 256 fp32
    float* ucol = bvp + 256;                              // 256 fp32

    int zb = (num_con + 1023) / 1024;
    prep0_kernel<<<zb + 256, 256, 0, stream>>>(
        counts, num_con, msg_W, msg_b, upd_W, w12b, bvp, ucol, zb);

    fill_kernel<<<(E + 255) / 256, 256, 0, stream>>>(src, dst, counts, eidx, E);

    ygemm_kernel<<<1024, 256, 0, stream>>>(x_var, w12b, yv, n_var, ntiles_v);

    gatherln_kernel<<<(num_con + 3) / 4, 256, 0, stream>>>(
        yv, counts, eidx, clue, bvp, ucol, upd_b, ln_w, ln_b,
        (float*)d_out, num_con);
}